// Round 4
// baseline (673.756 us; speedup 1.0000x reference)
//
#include <hip/hip_runtime.h>

#define N_IN 2000000
#define N_OUT 250000
#define C_IN 32
#define C_OUT 64
#define K_VOL 8
#define EPS 1e-5f
#define CAP 32

#define PT_BLOCKS 7813         // ceil(N_IN/256)
#define G3_BLOCKS 7813         // ceil(15625 wave-groups / 2)

typedef __attribute__((ext_vector_type(8))) short short8;
typedef __attribute__((ext_vector_type(4))) float f32x4;

// ======== tier-1 workspace layout (int units) ========
// [0 .. 249999]        cnt[250000]
// [250000 .. 266383]   WHL (bf16 hi[16384] + lo[16384] ushorts = 64KB)
// [266384 .. 266767]   smalls: sums[64], sumsq[64], AB[128]
// [266768 .. 8266767]  rlist[250000*32]
#define T1_WT     250000
#define T1_SMALL  266384
#define T1_RLIST  266768
#define T1_NEED_BYTES ((size_t)(T1_RLIST + N_OUT * CAP) * 4)

// ======== tier-2 (round-2 CSR) workspace layout ========
#define FP_WT        250368
#define FP_BSUM      266752
#define FP_SMALL     267776
#define FP_RLIST     268288
#define FP_NEED_BYTES ((size_t)(FP_RLIST + N_IN) * 4)
#define N_SCAN 250112
#define N_SBLK 977
#define N_GROUPS 31250
#define GCONV_BLOCKS 7813

// ==================== tier-1: scatter + weight hi/lo fragment pack ====================
// whl element order: idx = ((c*4 + t)*64 + lane)*8 + kp ; hi at [idx], lo at [16384+idx]
__global__ __launch_bounds__(256) void k_scat2(const int* __restrict__ out_idx,
                                               const int* __restrict__ offs,
                                               const float* __restrict__ w,
                                               int* __restrict__ cnt,
                                               int* __restrict__ rlist,
                                               ushort* __restrict__ whl) {
    int b = blockIdx.x;
    if (b < PT_BLOCKS) {
        int i = b * 256 + threadIdx.x;
        if (i < N_IN) {
            int o = out_idx[i];
            int pos = atomicAdd(&cnt[o], 1);
            if (pos < CAP) rlist[o * CAP + pos] = i | (offs[i] << 21);
        }
    } else {
        int e = (b - PT_BLOCKS) * 256 + threadIdx.x;   // 0..16383
        int c = e >> 11, t = (e >> 9) & 3, l = (e >> 3) & 63, kp = e & 7;
        int j = 4 * c + (l >> 4);
        int n = t * 16 + (l & 15);
        float v = w[kp * 2048 + j * 64 + n];
        unsigned bits = __float_as_uint(v);
        float lo = v - __uint_as_float(bits & 0xFFFF0000u);
        whl[e]         = (ushort)(bits >> 16);
        whl[16384 + e] = (ushort)(__float_as_uint(lo) >> 16);
    }
}

// ==================== tier-1: build-in-LDS + split-bf16 MFMA GEMM ====================
// Wave-private XS[16 rows][289]: value (row r, j, kp) at r*289 + j*9 + kp.
// Logical K axis: kappa = j*8 + kp (dense 256). No inter-wave sharing, no barriers.
__global__ __launch_bounds__(128) void k_gconv3(const float* __restrict__ xf,
                                                const int* __restrict__ cnt,
                                                const int* __restrict__ rlist,
                                                const ushort* __restrict__ whl,
                                                float* __restrict__ out) {
    __shared__ float vxl[2 * 4640];
    int lane = threadIdx.x & 63;
    int wv = threadIdx.x >> 6;
    int g = blockIdx.x * 2 + wv;
    int base = g * 16;
    if (base >= N_OUT) return;
    float* VX = vxl + wv * 4640;

    // ---- zero XS (16*289 = 4624 floats = 1156 float4, 16B-aligned) ----
    float4* z4 = (float4*)VX;
    float4 zz = make_float4(0.f, 0.f, 0.f, 0.f);
#pragma unroll
    for (int i = 0; i < 19; ++i) {
        int p = i * 64 + lane;
        if (p < 1156) z4[p] = zz;
    }

    int slot = lane >> 3, jq = lane & 7;
    // ---- prefetch counts + 4 point-batches (rows 0-7 / 8-15, slots 0-7 / 8-15) ----
    int cv = cnt[base + (lane & 15)];
    const int* rbase = rlist + (size_t)base * CAP;
    int pkA = rbase[slot * CAP + jq];
    int pkB = rbase[(8 + slot) * CAP + jq];
    int pkC = rbase[slot * CAP + 8 + jq];
    int pkD = rbase[(8 + slot) * CAP + 8 + jq];

#pragma unroll
    for (int r = 0; r < 16; ++r) {
        int cr = __builtin_amdgcn_readlane(cv, r);
        if (cr > CAP) cr = CAP;
        if (cr == 0) continue;
        // batch 0: slots 0-7
        {
            int pk = __shfl(r < 8 ? pkA : pkB, (r & 7) * 8 + slot, 64);
            int idx = pk & 0x1FFFFF; if (idx > N_IN - 1) idx = N_IN - 1;
            int kp = (pk >> 21) & 7;
            const float4 x = *(const float4*)(xf + (size_t)idx * 32 + jq * 4);
            float* dst = VX + r * 289 + 36 * jq + kp;
            if (slot < cr) {
                atomicAdd(dst + 0,  x.x);
                atomicAdd(dst + 9,  x.y);
                atomicAdd(dst + 18, x.z);
                atomicAdd(dst + 27, x.w);
            }
        }
        // batch 1: slots 8-15
        if (cr > 8) {
            int pk = __shfl(r < 8 ? pkC : pkD, (r & 7) * 8 + slot, 64);
            int idx = pk & 0x1FFFFF; if (idx > N_IN - 1) idx = N_IN - 1;
            int kp = (pk >> 21) & 7;
            const float4 x = *(const float4*)(xf + (size_t)idx * 32 + jq * 4);
            float* dst = VX + r * 289 + 36 * jq + kp;
            if (8 + slot < cr) {
                atomicAdd(dst + 0,  x.x);
                atomicAdd(dst + 9,  x.y);
                atomicAdd(dst + 18, x.z);
                atomicAdd(dst + 27, x.w);
            }
        }
        // batches 2-3: slots 16-31 (rare)
        if (cr > 16) {
            for (int p0 = 16; p0 < cr; p0 += 8) {
                int pp = p0 + slot; if (pp > cr - 1) pp = cr - 1;
                int pk = rlist[((size_t)base + r) * CAP + pp];
                int idx = pk & 0x1FFFFF; if (idx > N_IN - 1) idx = N_IN - 1;
                int kp = (pk >> 21) & 7;
                const float4 x = *(const float4*)(xf + (size_t)idx * 32 + jq * 4);
                float* dst = VX + r * 289 + 36 * jq + kp;
                if (p0 + slot < cr) {
                    atomicAdd(dst + 0,  x.x);
                    atomicAdd(dst + 9,  x.y);
                    atomicAdd(dst + 18, x.z);
                    atomicAdd(dst + 27, x.w);
                }
            }
        }
    }

    // same-wave DS ops are in-order; fence the compiler, drain lgkm
    __builtin_amdgcn_sched_barrier(0);
    asm volatile("s_waitcnt lgkmcnt(0)" ::: "memory");
    __builtin_amdgcn_sched_barrier(0);

    // ---- GEMM: out[16x64] = XS[16x256] @ W[256x64], split-bf16 MFMA ----
    int o = lane >> 4;       // k-octet -> j = 4c + o
    int n16 = lane & 15;
    f32x4 zacc = {0.f, 0.f, 0.f, 0.f};
    f32x4 acc0 = zacc, acc1 = zacc, acc2 = zacc, acc3 = zacc;
    const short8* wh = (const short8*)whl;
    const short8* wl = wh + 2048;

#pragma unroll
    for (int c = 0; c < 8; ++c) {
        const float* src = VX + n16 * 289 + (4 * c + o) * 9;
        float a[8];
#pragma unroll
        for (int e = 0; e < 8; ++e) a[e] = src[e];
        short8 ahi, alo;
#pragma unroll
        for (int e = 0; e < 8; ++e) {
            unsigned b = __float_as_uint(a[e]);
            ahi[e] = (short)(b >> 16);
            float lo = a[e] - __uint_as_float(b & 0xFFFF0000u);
            alo[e] = (short)(__float_as_uint(lo) >> 16);
        }
#pragma unroll
        for (int t = 0; t < 4; ++t) {
            short8 bh = wh[(c * 4 + t) * 64 + lane];
            short8 bl = wl[(c * 4 + t) * 64 + lane];
            f32x4* pa = (t == 0) ? &acc0 : (t == 1) ? &acc1 : (t == 2) ? &acc2 : &acc3;
            *pa = __builtin_amdgcn_mfma_f32_16x16x32_bf16(ahi, bh, *pa, 0, 0, 0);
            *pa = __builtin_amdgcn_mfma_f32_16x16x32_bf16(alo, bh, *pa, 0, 0, 0);
            *pa = __builtin_amdgcn_mfma_f32_16x16x32_bf16(ahi, bl, *pa, 0, 0, 0);
        }
    }

    // ---- store: D col = lane&15, row = (lane>>4)*4 + reg ----
#pragma unroll
    for (int t = 0; t < 4; ++t) {
        f32x4 a = (t == 0) ? acc0 : (t == 1) ? acc1 : (t == 2) ? acc2 : acc3;
#pragma unroll
        for (int reg = 0; reg < 4; ++reg)
            out[(size_t)(base + o * 4 + reg) * 64 + t * 16 + n16] = a[reg];
    }
}

// ==================== shared post-passes ====================

__global__ __launch_bounds__(256) void k_stats(const float* __restrict__ out,
                                               float* __restrict__ sums,
                                               float* __restrict__ sumsq) {
    int t = threadIdx.x;
    long stride = (long)gridDim.x * 256;
    float s = 0.f, q = 0.f;
    for (long i = (long)blockIdx.x * 256 + t; i < (long)N_OUT * C_OUT; i += stride) {
        float v = out[i];
        s += v;
        q = fmaf(v, v, q);
    }
    __shared__ float ls[256], lq[256];
    ls[t] = s; lq[t] = q;
    __syncthreads();
    if (t < 64) {
        s = ls[t] + ls[t + 64] + ls[t + 128] + ls[t + 192];
        q = lq[t] + lq[t + 64] + lq[t + 128] + lq[t + 192];
        atomicAdd(&sums[t], s);
        atomicAdd(&sumsq[t], q);
    }
}

__global__ __launch_bounds__(256) void k_ctxprep(const float* __restrict__ context,
                                                 const float* __restrict__ ctx_w,
                                                 const float* __restrict__ sums,
                                                 const float* __restrict__ sumsq,
                                                 const float* __restrict__ gamma,
                                                 const float* __restrict__ beta,
                                                 const int* __restrict__ cond,
                                                 float* __restrict__ AB) {
    __shared__ float part[256];
    __shared__ float ctxv[128];
    int t = threadIdx.x;
    int col = t & 127, half = t >> 7;
    float s = 0.f;
    for (int r = half * 128; r < half * 128 + 128; ++r)
        s = fmaf(context[r], ctx_w[r * 128 + col], s);
    part[t] = s;
    __syncthreads();
    if (t < 128) ctxv[t] = part[t] + part[t + 128];
    __syncthreads();
    if (t < 64) {
        float mean = sums[t] * (1.f / N_OUT);
        float var  = sumsq[t] * (1.f / N_OUT) - mean * mean;
        float inv  = rsqrtf(var + EPS);
        int cd = cond[0];
        float gm = gamma[cd * C_OUT + t], bt = beta[cd * C_OUT + t];
        float sc = 1.f + ctxv[t];
        float sh = ctxv[64 + t];
        AB[t]      = inv * gm * sc;
        AB[64 + t] = (bt - mean * inv * gm) * sc + sh;
    }
}

__global__ __launch_bounds__(256) void k_norm(float* __restrict__ out,
                                              const float* __restrict__ AB) {
    __shared__ float4 lA[16], lB[16];
    int t = threadIdx.x;
    if (t < 16) {
        lA[t] = ((const float4*)AB)[t];
        lB[t] = ((const float4*)AB)[16 + t];
    }
    __syncthreads();
    const long total4 = (long)N_OUT * C_OUT / 4;
    long stride = (long)gridDim.x * 256;
    for (long i = (long)blockIdx.x * 256 + t; i < total4; i += stride) {
        float4 v = ((float4*)out)[i];
        float4 a = lA[i & 15], b = lB[i & 15];
        v.x = fmaxf(fmaf(v.x, a.x, b.x), 0.f);
        v.y = fmaxf(fmaf(v.y, a.y, b.y), 0.f);
        v.z = fmaxf(fmaf(v.z, a.z, b.z), 0.f);
        v.w = fmaxf(fmaf(v.w, a.w, b.w), 0.f);
        ((float4*)out)[i] = v;
    }
}

// ==================== tier-2 (round-2 CSR path, validated) ====================

__global__ __launch_bounds__(256) void k_wt(const float* __restrict__ w,
                                            float* __restrict__ WT) {
    int e = blockIdx.x * 256 + threadIdx.x;
    int k = e >> 11, j = (e >> 6) & 31, c = e & 63;
    WT[k * 2048 + (j >> 2) * 256 + c * 4 + (j & 3)] = w[e];
}

__global__ __launch_bounds__(256) void k_hist2(const int* __restrict__ out_idx,
                                               int* __restrict__ cnt) {
    int i = blockIdx.x * 256 + threadIdx.x;
    if (i < N_IN) atomicAdd(&cnt[out_idx[i]], 1);
}

__global__ __launch_bounds__(256) void k_scan_a(const int* __restrict__ cnt,
                                                int* __restrict__ S,
                                                int* __restrict__ bsum) {
    __shared__ int sh[256];
    int t = threadIdx.x;
    int g = blockIdx.x * 256 + t;
    int v = cnt[g];
    sh[t] = v;
    __syncthreads();
#pragma unroll
    for (int off = 1; off < 256; off <<= 1) {
        int a = (t >= off) ? sh[t - off] : 0;
        __syncthreads();
        sh[t] += a;
        __syncthreads();
    }
    S[g] = sh[t] - v;
    if (t == 255) bsum[blockIdx.x] = sh[255];
}

__global__ __launch_bounds__(1024) void k_scan_b(int* __restrict__ bsum) {
    __shared__ int sh[1024];
    int t = threadIdx.x;
    int v = (t < N_SBLK) ? bsum[t] : 0;
    sh[t] = v;
    __syncthreads();
#pragma unroll
    for (int off = 1; off < 1024; off <<= 1) {
        int a = (t >= off) ? sh[t - off] : 0;
        __syncthreads();
        sh[t] += a;
        __syncthreads();
    }
    bsum[t] = sh[t] - v;
}

__global__ __launch_bounds__(256) void k_scan_c(int* __restrict__ S,
                                                const int* __restrict__ bsum) {
    int g = blockIdx.x * 256 + threadIdx.x;
    S[g] += bsum[blockIdx.x];
}

__global__ __launch_bounds__(256) void k_scatter2(const int* __restrict__ out_idx,
                                                  const int* __restrict__ offs,
                                                  int* __restrict__ S,
                                                  int* __restrict__ rlist) {
    int i = blockIdx.x * 256 + threadIdx.x;
    if (i < N_IN) {
        int o = out_idx[i];
        int pos = atomicAdd(&S[o], 1);
        rlist[pos] = i | (offs[i] << 21);
    }
}

__global__ __launch_bounds__(256) void k_gconv_c(const float* __restrict__ xf,
                                                 const int* __restrict__ Sarr,
                                                 const int* __restrict__ rlist,
                                                 const float* __restrict__ WG,
                                                 float* __restrict__ out) {
    int lane = threadIdx.x & 63;
    int wv = threadIdx.x >> 6;
    int group = blockIdx.x * 4 + wv;
    if (group >= N_GROUPS) return;
    int base = group * 8;
    int kq = lane >> 3, jq = lane & 7;
    int slot = lane >> 3;

    float4 vx[8];
    unsigned km[8];
#pragma unroll
    for (int r = 0; r < 8; ++r) {
        vx[r] = make_float4(0.f, 0.f, 0.f, 0.f);
        km[r] = 0u;
    }

#pragma unroll
    for (int r = 0; r < 8; ++r) {
        int s = Sarr[base + r];
        int e = Sarr[base + r + 1];
        unsigned m = 0;
        for (int p = s; p < e; p += 8) {
            int pp = p + slot;
            if (pp >= e) pp = e - 1;
            int pkv = rlist[pp];
#pragma unroll
            for (int ss = 0; ss < 8; ++ss) {
                if (p + ss >= e) break;
                int pks = __builtin_amdgcn_readlane(pkv, ss * 8);
                int idx = pks & 0x1FFFFF;
                int kp = (pks >> 21) & 7;
                m |= 1u << kp;
                if (kq == kp) {
                    const float4 xq = *(const float4*)(xf + (size_t)idx * 32 + jq * 4);
                    vx[r].x += xq.x; vx[r].y += xq.y;
                    vx[r].z += xq.z; vx[r].w += xq.w;
                }
            }
        }
        km[r] = m;
    }

    unsigned anym = km[0] | km[1] | km[2] | km[3] | km[4] | km[5] | km[6] | km[7];
    float acc[8];
#pragma unroll
    for (int r = 0; r < 8; ++r) acc[r] = 0.f;

    for (int k = 0; k < 8; ++k) {
        if (!((anym >> k) & 1u)) continue;
        const float4* wp = ((const float4*)WG) + k * 512;
        float4 w[8];
#pragma unroll
        for (int q = 0; q < 8; ++q) w[q] = wp[q * 64 + lane];
#pragma unroll
        for (int r = 0; r < 8; ++r) {
            if (!((km[r] >> k) & 1u)) continue;
#pragma unroll
            for (int q = 0; q < 8; ++q) {
                int ls = k * 8 + q;
                float a0 = __int_as_float(__builtin_amdgcn_readlane(__float_as_int(vx[r].x), ls));
                float a1 = __int_as_float(__builtin_amdgcn_readlane(__float_as_int(vx[r].y), ls));
                float a2 = __int_as_float(__builtin_amdgcn_readlane(__float_as_int(vx[r].z), ls));
                float a3 = __int_as_float(__builtin_amdgcn_readlane(__float_as_int(vx[r].w), ls));
                acc[r] = fmaf(a0, w[q].x, acc[r]);
                acc[r] = fmaf(a1, w[q].y, acc[r]);
                acc[r] = fmaf(a2, w[q].z, acc[r]);
                acc[r] = fmaf(a3, w[q].w, acc[r]);
            }
        }
    }

#pragma unroll
    for (int r = 0; r < 8; ++r)
        out[(size_t)(base + r) * 64 + lane] = acc[r];
}

__global__ void k_prep(const float* __restrict__ sums, const float* __restrict__ sumsq,
                       const float* __restrict__ gamma, const float* __restrict__ beta,
                       const int* __restrict__ cond, const float* __restrict__ ctx_out,
                       float* __restrict__ AB) {
    int c = threadIdx.x;
    float mean = sums[c] * (1.f / N_OUT);
    float var  = sumsq[c] * (1.f / N_OUT) - mean * mean;
    float inv  = rsqrtf(var + EPS);
    int cd = cond[0];
    float g = gamma[cd * C_OUT + c], b = beta[cd * C_OUT + c];
    float sc = 1.f + ctx_out[c];
    float sh = ctx_out[64 + c];
    AB[c]      = inv * g * sc;
    AB[64 + c] = (b - mean * inv * g) * sc + sh;
}

__global__ __launch_bounds__(256) void k_ctx(const float* __restrict__ context,
                                             const float* __restrict__ ctx_w,
                                             float* __restrict__ ctx_out) {
    int t = threadIdx.x;
    int col = t & 127, half = t >> 7;
    float s = 0.f;
    for (int r = half * 128; r < half * 128 + 128; ++r)
        s = fmaf(context[r], ctx_w[r * 128 + col], s);
    __shared__ float part[256];
    part[t] = s;
    __syncthreads();
    if (t < 128) ctx_out[t] = part[t] + part[t + 128];
}

// ============================== launch ==============================

extern "C" void kernel_launch(void* const* d_in, const int* in_sizes, int n_in,
                              void* d_out, int out_size, void* d_ws, size_t ws_size,
                              hipStream_t stream) {
    const float* in_feats = (const float*)d_in[0];
    const int*   offs     = (const int*)d_in[1];
    const int*   out_idx  = (const int*)d_in[2];
    const float* weight   = (const float*)d_in[3];
    const float* gamma    = (const float*)d_in[4];
    const float* beta     = (const float*)d_in[5];
    const float* context  = (const float*)d_in[6];
    const float* ctx_w    = (const float*)d_in[7];
    const int*   cond     = (const int*)d_in[8];
    float* out = (float*)d_out;

    int*   wsi = (int*)d_ws;
    float* wsf = (float*)d_ws;

    if (ws_size >= T1_NEED_BYTES) {
        // -------- tier-1: direct scatter + LDS build + split-bf16 MFMA --------
        int*    cnt    = wsi;
        ushort* whl    = (ushort*)(wsf + T1_WT);
        float*  smalls = wsf + T1_SMALL;          // sums[64], sumsq[64], AB[128]
        int*    rlist  = wsi + T1_RLIST;

        hipMemsetAsync(cnt, 0, (size_t)N_OUT * 4, stream);
        hipMemsetAsync(smalls, 0, 128 * 4, stream);

        k_scat2<<<PT_BLOCKS + 64, 256, 0, stream>>>(out_idx, offs, weight, cnt, rlist, whl);
        k_gconv3<<<G3_BLOCKS, 128, 0, stream>>>(in_feats, cnt, rlist, whl, out);

        k_stats<<<2048, 256, 0, stream>>>(out, smalls, smalls + 64);
        k_ctxprep<<<1, 256, 0, stream>>>(context, ctx_w, smalls, smalls + 64,
                                         gamma, beta, cond, smalls + 128);
        k_norm<<<2048, 256, 0, stream>>>(out, smalls + 128);
    } else {
        // -------- tier-2: round-2 CSR path (validated) --------
        int*   S_base = wsi + 1;
        float* WT     = wsf + FP_WT;
        int*   bsum   = wsi + FP_BSUM;
        float* smalls = wsf + FP_SMALL;
        int*   rlist  = wsi + FP_RLIST;
        int*   cnt    = rlist;

        hipMemsetAsync(wsi, 0, 4, stream);
        hipMemsetAsync(cnt, 0, (size_t)N_SCAN * 4, stream);
        hipMemsetAsync(smalls, 0, 384 * 4, stream);

        k_hist2<<<PT_BLOCKS, 256, 0, stream>>>(out_idx, cnt);
        k_scan_a<<<N_SBLK, 256, 0, stream>>>(cnt, S_base, bsum);
        k_scan_b<<<1, 1024, 0, stream>>>(bsum);
        k_scan_c<<<N_SBLK, 256, 0, stream>>>(S_base, bsum);
        k_wt<<<64, 256, 0, stream>>>(weight, WT);
        k_scatter2<<<PT_BLOCKS, 256, 0, stream>>>(out_idx, offs, S_base, rlist);
        k_gconv_c<<<GCONV_BLOCKS, 256, 0, stream>>>(in_feats, wsi, rlist, WT, out);

        k_stats<<<2048, 256, 0, stream>>>(out, smalls, smalls + 64);
        k_ctx<<<1, 256, 0, stream>>>(context, ctx_w, smalls + 128);
        k_prep<<<1, 64, 0, stream>>>(smalls, smalls + 64, gamma, beta,
                                     cond, smalls + 128, smalls + 256);
        k_norm<<<2048, 256, 0, stream>>>(out, smalls + 256);
    }
}